// Round 6
// baseline (232.734 us; speedup 1.0000x reference)
//
#include <hip/hip_runtime.h>

// BilateralGrid apply.
// R1: LDS fp16 gather (118 us). R2: packed v_pk_fma_f16 (103). R3: padded
// b64 layout (90; conflicts 3.2e7->2.58e7, b64 floor). R4: b128 split layout
// (conflicts 1.295e7) but launch_bounds clamp => spills => 127. R6: clamp
// removed: 103, latency-bound. R7: next-quad prefetch + rotation: 88.5.
// Counters at R7: LDS busy ~58% (123K cy), VALU 28%, sum ~86% => the two
// pipes run SERIALLY — convoy: every wave does {12 ds_read -> wait -> 48
// FMA} in lockstep from the same barrier, so LDS idles during FMA phases.
// R8: corner-granularity software pipeline. Precompute all 4 pixels'
// addresses + all 16 (u0,u1) f16 weight pairs per quad (no LDS dep), then
// 16 slots: issue slot s+1's 3 ds_read_b128 into ping-pong regs, FMA slot
// s. Per-wave time -> max(LDS, VALU) instead of sum. Per-pixel 12B stores
// replace O[12] batching to hold VGPR down.
// Layout (unchanged): A = rows 0,1 [y][x][z][8]h, XSA=72; B = row 2 z-pair
// duplicated [y][x][zp][8]h, XSB=56. 12 b128/px, 16B-aligned. 64 KB LDS.

typedef _Float16 h2 __attribute__((ext_vector_type(2)));
typedef _Float16 h4 __attribute__((ext_vector_type(4)));
typedef _Float16 h8 __attribute__((ext_vector_type(8)));

#define BLOCK 1024

#define XSA 72
#define YSA 1152
#define NA  18432
#define XSB 56
#define YSB 896
#define NB  14336

__global__ __launch_bounds__(BLOCK) void bilateral_apply(
    const float* __restrict__ pixels,
    const float* __restrict__ coords,
    const float* __restrict__ grid,
    float* __restrict__ out,
    int n4)
{
    __shared__ alignas(16) _Float16 gA[NA];  // 36864 B
    __shared__ alignas(16) _Float16 gB[NB];  // 28672 B  (total 64 KB)

    const int stride = gridDim.x * BLOCK;
    int t = blockIdx.x * BLOCK + threadIdx.x;

    // First quad's loads before staging: HBM latency hides under stage+barrier.
    long long base = (long long)t * 4;
    const float* pp = pixels + base * 3;
    const float* cp = coords + base * 2;
    float4 pa = *(const float4*)(pp + 0);
    float4 pb = *(const float4*)(pp + 4);
    float4 pc = *(const float4*)(pp + 8);
    float4 ca = *(const float4*)(cp + 0);
    float4 cb = *(const float4*)(cp + 4);

    // Cooperative stage: fp32 grid -> fp16 LDS, split layout.
    for (int cell = threadIdx.x; cell < 2048; cell += BLOCK) {
        int y = cell >> 7;
        int x = (cell >> 3) & 15;
        int z = cell & 7;
        const float4* src = (const float4*)(grid + (long long)cell * 12);
        float4 v0 = src[0], v1 = src[1], v2 = src[2];
        h8 a = { (_Float16)v0.x, (_Float16)v0.y, (_Float16)v0.z, (_Float16)v0.w,
                 (_Float16)v1.x, (_Float16)v1.y, (_Float16)v1.z, (_Float16)v1.w };
        *(h8*)(gA + y * YSA + x * XSA + z * 8) = a;   // 16B aligned
        h4 b = { (_Float16)v2.x, (_Float16)v2.y, (_Float16)v2.z, (_Float16)v2.w };
        _Float16* bb = gB + y * YSB + x * XSB;
        if (z <= 6) *(h4*)(bb + z * 8) = b;           // lo half of pair z
        if (z >= 1) *(h4*)(bb + (z - 1) * 8 + 4) = b; // hi half of pair z-1
    }
    __syncthreads();

    #pragma clang loop unroll(disable)
    while (true) {
        // Prefetch next quad while this one computes.
        int tn = t + stride;
        bool more = tn < n4;
        float4 npa, npb, npc, nca, ncb;
        if (more) {
            long long nbase = (long long)tn * 4;
            const float* npp = pixels + nbase * 3;
            const float* ncp = coords + nbase * 2;
            npa = *(const float4*)(npp + 0);
            npb = *(const float4*)(npp + 4);
            npc = *(const float4*)(npp + 8);
            nca = *(const float4*)(ncp + 0);
            ncb = *(const float4*)(ncp + 4);
        }
        __builtin_amdgcn_sched_barrier(0);  // pin prefetch issue above compute

        float R[4]  = {pa.x, pa.w, pb.z, pc.y};
        float G[4]  = {pa.y, pb.x, pb.w, pc.z};
        float Bc[4] = {pa.z, pb.y, pc.x, pc.w};
        float CX[4] = {ca.x, ca.z, cb.x, cb.z};
        float CY[4] = {ca.y, ca.w, cb.y, cb.w};

        // Upfront (pure VALU, no LDS dep): per-pixel base addresses and all
        // 16 packed (u0,u1) corner weights. All indices compile-time.
        int abase[4], bbase[4];
        h2 u01[16];
        #pragma unroll
        for (int k = 0; k < 4; ++k) {
            float guide = 0.2126f * R[k] + 0.7152f * G[k] + 0.0722f * Bc[k];
            float gx = fminf(fmaxf(CX[k] * 15.0f, 0.0f), 14.999f);
            float gy = fminf(fmaxf(CY[k] * 15.0f, 0.0f), 14.999f);
            float gz = fminf(fminf(fmaxf(guide, 0.0f), 1.0f) * 7.0f, 6.999f);
            int x0 = (int)gx, y0 = (int)gy, z0 = (int)gz;
            float fx = gx - (float)x0;
            float fy = gy - (float)y0;
            float fz = gz - (float)z0;
            abase[k] = y0 * YSA + x0 * XSA + z0 * 8;
            bbase[k] = y0 * YSB + x0 * XSB + z0 * 8;
            float wz0 = 1.0f - fz, wz1 = fz;
            float cw0 = (1.0f - fy) * (1.0f - fx);
            float cw1 = (1.0f - fy) * fx;
            float cw2 = fy * (1.0f - fx);
            float cw3 = fy * fx;
            h2 w0 = {(_Float16)(cw0 * wz0), (_Float16)(cw0 * wz1)}; u01[4*k+0] = w0;
            h2 w1 = {(_Float16)(cw1 * wz0), (_Float16)(cw1 * wz1)}; u01[4*k+1] = w1;
            h2 w2 = {(_Float16)(cw2 * wz0), (_Float16)(cw2 * wz1)}; u01[4*k+2] = w2;
            h2 w3 = {(_Float16)(cw3 * wz0), (_Float16)(cw3 * wz1)}; u01[4*k+3] = w3;
        }

        // 16-slot pipelined gather+FMA: slot s data in buffer (s even: A,
        // s odd: B); slot s issues slot s+1's reads into the other buffer.
        h8 a0A, a1A, bpA, a0B, a1B, bpB;
        {
            const h8* qa = (const h8*)(gA + abase[0]);
            a0A = qa[0]; a1A = qa[1];
            bpA = *(const h8*)(gB + bbase[0]);
        }
        h8 accA = (h8)(_Float16)0.0f;
        h4 accB = (h4)(_Float16)0.0f;
        #pragma unroll
        for (int s = 0; s < 16; ++s) {
            const int k = s >> 2, c = s & 3;
            if (s < 15) {
                const int kn = (s + 1) >> 2, cn = (s + 1) & 3;
                const int ao = ((cn & 1) ? XSA : 0) + ((cn & 2) ? YSA : 0);
                const int bo = ((cn & 1) ? XSB : 0) + ((cn & 2) ? YSB : 0);
                const h8* qa = (const h8*)(gA + abase[kn] + ao);
                if ((s & 1) == 0) {
                    a0B = qa[0]; a1B = qa[1];
                    bpB = *(const h8*)(gB + bbase[kn] + bo);
                } else {
                    a0A = qa[0]; a1A = qa[1];
                    bpA = *(const h8*)(gB + bbase[kn] + bo);
                }
            }
            h8 ca0 = (s & 1) ? a0B : a0A;
            h8 ca1 = (s & 1) ? a1B : a1A;
            h8 cbp = (s & 1) ? bpB : bpA;
            h2 u = u01[s];
            _Float16 u0 = u.x, u1 = u.y;
            h8 u0v8 = {u0, u0, u0, u0, u0, u0, u0, u0};
            h8 u1v8 = {u1, u1, u1, u1, u1, u1, u1, u1};
            h4 u0v4 = {u0, u0, u0, u0};
            h4 u1v4 = {u1, u1, u1, u1};
            if (c == 0) {
                accA = (h8)(_Float16)0.0f;
                accB = (h4)(_Float16)0.0f;
            }
            h4 blo = __builtin_shufflevector(cbp, cbp, 0, 1, 2, 3);
            h4 bhi = __builtin_shufflevector(cbp, cbp, 4, 5, 6, 7);
            accA = ca0 * u0v8 + (ca1 * u1v8 + accA);   // v_pk_fma_f16
            accB = blo * u0v4 + (bhi * u1v4 + accB);
            if (c == 3) {
                h4 acc0 = __builtin_shufflevector(accA, accA, 0, 1, 2, 3);
                h4 acc1 = __builtin_shufflevector(accA, accA, 4, 5, 6, 7);
                float r = R[k], g = G[k], b = Bc[k];
                float o0 = fmaf((float)acc0.x, r, fmaf((float)acc0.y, g,
                           fmaf((float)acc0.z, b, (float)acc0.w)));
                float o1 = fmaf((float)acc1.x, r, fmaf((float)acc1.y, g,
                           fmaf((float)acc1.z, b, (float)acc1.w)));
                float o2 = fmaf((float)accB.x, r, fmaf((float)accB.y, g,
                           fmaf((float)accB.z, b, (float)accB.w)));
                float* op = out + (base + k) * 3;
                op[0] = o0; op[1] = o1; op[2] = o2;
            }
        }

        if (!more) break;
        pa = npa; pb = npb; pc = npc; ca = nca; cb = ncb;
        t = tn;
        base = (long long)t * 4;
    }
}

extern "C" void kernel_launch(void* const* d_in, const int* in_sizes, int n_in,
                              void* d_out, int out_size, void* d_ws, size_t ws_size,
                              hipStream_t stream) {
    const float* pixels = (const float*)d_in[0];
    const float* coords = (const float*)d_in[1];
    const float* grid   = (const float*)d_in[2];
    float* out = (float*)d_out;

    int npix = in_sizes[0] / 3;   // 8,294,400 (divisible by 4)
    int n4   = npix / 4;          // 2,073,600 quads
    // 64 KB LDS/block => 2 blocks/CU. 512 = 2*256 CUs.
    int nblk = 512;
    bilateral_apply<<<nblk, BLOCK, 0, stream>>>(pixels, coords, grid, out, n4);
}